// Round 14
// baseline (137.113 us; speedup 1.0000x reference)
//
#include <hip/hip_runtime.h>
#include <stdint.h>
#include <stddef.h>

#define DIM 256
#define NB 16
#define HH 56
#define WW 56
#define HWP (HH*WW)          // 3136
#define PH 62
#define PW 62
#define NPIX (NB*HWP)        // 50176
#define EPSV 1e-5f

using f32x4  = __attribute__((ext_vector_type(4))) float;
using bf16x8 = __attribute__((ext_vector_type(8))) __bf16;

static __device__ __forceinline__ unsigned short f2bf(float f) {
    union { float f; unsigned u; } v; v.f = f;
    unsigned r = v.u + 0x7FFFu + ((v.u >> 16) & 1u);
    return (unsigned short)(r >> 16);
}
static __device__ __forceinline__ float bf2f(unsigned short u) {
    union { unsigned u; float f; } v; v.u = ((unsigned)u) << 16; return v.f;
}
static __device__ __forceinline__ float silu_f(float z) {
    return z / (1.f + __expf(-z));
}

// ---------------- Fused prep: depthwise7 (blocks 0..4095), xpad (4096..8063),
//                  weights (8064..8319) — independent work, one launch ----------------
// x reads vectorized as float4 (56 % 4 == 0 -> no row crossing) per G13.
__global__ __launch_bounds__(256)
void fused_prep(const float* __restrict__ x,
                const float* __restrict__ w3, const float* __restrict__ g1,
                const float* __restrict__ b1, const float* __restrict__ m1,
                const float* __restrict__ v1, const float* __restrict__ w1,
                const float* __restrict__ g2, const float* __restrict__ b2,
                const float* __restrict__ m2, const float* __restrict__ v2,
                const float* __restrict__ dw7, const float* __restrict__ dwk,
                const float* __restrict__ g3, const float* __restrict__ b3,
                const float* __restrict__ m3, const float* __restrict__ v3,
                unsigned short* __restrict__ xpad, unsigned short* __restrict__ WkT,
                unsigned short* __restrict__ dwout, float* __restrict__ biasm,
                float* __restrict__ sc3, float* __restrict__ bi3)
{
    __shared__ float shbuf[PH*64];                   // P3: plane[62][64]; P2: lds[64][57]
    int bid = blockIdx.x;
    int t = threadIdx.x;

    if (bid < 4096) {
        // ---------------- P3: depthwise 7x7, c = bid&255, b = bid>>8 ----------------
        float (*plane)[64] = (float(*)[64])shbuf;
        int c = bid & 255, b = bid >> 8;
#pragma unroll
        for (int j = 0; j < 4; ++j) {
            int idx = j*256 + t;
            if (idx < 992) ((f32x4*)plane)[idx] = (f32x4){0.f,0.f,0.f,0.f};
        }
        __syncthreads();
        const float* xp = x + ((size_t)b*DIM + c)*HWP;
#pragma unroll
        for (int j = 0; j < 4; ++j) {                // 784 float4 = 3136 f32
            int i4 = j*256 + t;
            if (i4 < 784) {
                f32x4 v = *(const f32x4*)&xp[i4*4];
                int px = i4*4;
                int h = px / 56, w = px % 56;
                float* dst = &plane[h + 3][w + 3];
                dst[0] = v[0]; dst[1] = v[1]; dst[2] = v[2]; dst[3] = v[3];
            }
        }
        float wr[49];
#pragma unroll
        for (int i = 0; i < 49; ++i) wr[i] = dw7[c*49 + i] + dwk[c*49 + i];  // uniform -> SGPR
        __syncthreads();
        unsigned short* op = dwout + ((size_t)b*DIM + c)*HWP;
#pragma unroll
        for (int j = 0; j < 2; ++j) {                // 392 octs = 56 rows x 7
            int q = j*256 + t;
            if (q < 392) {
                int h = q / 7, w0 = (q % 7)*8;
                float a[8] = {0.f,0.f,0.f,0.f,0.f,0.f,0.f,0.f};
#pragma unroll
                for (int dy = 0; dy < 7; ++dy) {
                    const float* row = &plane[h + dy][w0];
                    union { f32x4 v[4]; float s[16]; } rr;
                    rr.v[0] = *(const f32x4*)(row);
                    rr.v[1] = *(const f32x4*)(row + 4);
                    rr.v[2] = *(const f32x4*)(row + 8);
                    rr.v[3] = *(const f32x4*)(row + 12);
#pragma unroll
                    for (int dx = 0; dx < 7; ++dx) {
                        float wv = wr[dy*7 + dx];
#pragma unroll
                        for (int o = 0; o < 8; ++o) a[o] += rr.s[dx + o] * wv;
                    }
                }
                uint4 pk;
                pk.x = (unsigned)f2bf(a[0]) | ((unsigned)f2bf(a[1]) << 16);
                pk.y = (unsigned)f2bf(a[2]) | ((unsigned)f2bf(a[3]) << 16);
                pk.z = (unsigned)f2bf(a[4]) | ((unsigned)f2bf(a[5]) << 16);
                pk.w = (unsigned)f2bf(a[6]) | ((unsigned)f2bf(a[7]) << 16);
                *(uint4*)&op[h*WW + w0] = pk;
            }
        }
        return;
    }

    if (bid < 8064) {
        // ---------------- P2: xpad, idx -> (cc, ph, b) ----------------
        float (*lds)[57] = (float(*)[57])shbuf;
        int idx0 = bid - 4096;
        int cc = idx0 & 3;                           // channel chunk of 64
        int r62 = (idx0 >> 2);
        int ph = r62 % PH, b = r62 / PH;
        int c0 = cc*64;
        char* rowc = (char*)xpad + ((size_t)(b*PH + ph)*PW)*(DIM*2) + c0*2;

        if (ph < 3 || ph >= HH + 3) {
            uint4 z = {0u,0u,0u,0u};
#pragma unroll
            for (int j = 0; j < 2; ++j) {
                int idx = j*256 + t;
                if (idx < 496) {
                    int pix = idx >> 3, q = idx & 7;
                    *(uint4*)(rowc + (size_t)pix*(DIM*2) + q*16) = z;
                }
            }
            return;
        }
        if (t < 48) {
            int p = t >> 3, q = t & 7;
            int pw = (p < 3) ? p : (PW - 6 + p);     // 0,1,2, 59,60,61
            uint4 z = {0u,0u,0u,0u};
            *(uint4*)(rowc + (size_t)pw*(DIM*2) + q*16) = z;
        }
        int h = ph - 3;
#pragma unroll
        for (int j = 0; j < 4; ++j) {                // 896 float4 = 64 rows x 14
            int i4 = j*256 + t;
            if (i4 < 896) {
                int c = i4 / 14, w4 = (i4 % 14)*4;
                f32x4 v = *(const f32x4*)&x[((size_t)(b*DIM + c0 + c)*HH + h)*WW + w4];
                lds[c][w4] = v[0]; lds[c][w4+1] = v[1];
                lds[c][w4+2] = v[2]; lds[c][w4+3] = v[3];
            }
        }
        __syncthreads();
#pragma unroll
        for (int j = 0; j < 7; ++j) {                // 56*32 pairs = 1792 = 7*256
            int idx = j*256 + t;
            int w = idx >> 5, cp = idx & 31;
            unsigned lo = f2bf(lds[2*cp][w]);
            unsigned hi = f2bf(lds[2*cp+1][w]);
            unsigned val = lo | (hi << 16);
            *(unsigned*)(rowc + (size_t)(w + 3)*(DIM*2) + 4*cp) = val;
        }
        return;
    }

    // ---------------- P1: weights, co = bid - 8064, t = ci ----------------
    {
        int co = bid - 8064;
        float s1 = g1[co] * rsqrtf(v1[co] + EPSV);
        float s2 = g2[co] * rsqrtf(v2[co] + EPSV);
        float w1v = w1[co*DIM + t] * s2;
        const float* w3r = w3 + (size_t)(co*DIM + t)*9;
#pragma unroll
        for (int s = 0; s < 9; ++s) {
            float v = w3r[s]*s1 + (s == 4 ? w1v : 0.f);
            WkT[((size_t)s*DIM + co)*DIM + t] = f2bf(v);   // layout [tap][co][ci]
        }
        if (t == 0) {
            biasm[co] = (b1[co] - m1[co]*s1) + (b2[co] - m2[co]*s2);
            float s3 = g3[co] * rsqrtf(v3[co] + EPSV);
            sc3[co] = s3;
            bi3[co] = b3[co] - m3[co]*s3;
        }
    }
}

// ---------------- Main: implicit-GEMM conv3x3, 128x128 tile, single-buffer 4 blocks/CU -
// R13-validated structure + T1 bijective XCD swizzle (784 = 8 x 98 exact): blocks with
// the same id%8 (same XCD under round-robin dispatch) get CONTIGUOUS work chunks, so the
// co-pair sharing an A-tile and neighboring pixel-tiles hit the same per-XCD L2
// (working set ~3.2MB xpad slice + 1.2MB B < 4MB L2) -> shorter stage drains.
__global__ __launch_bounds__(256, 4)
void main_conv(const unsigned short* __restrict__ xpad, const unsigned short* __restrict__ WkT,
               const unsigned short* __restrict__ dwo, const float* __restrict__ biasm,
               const float* __restrict__ sc3, const float* __restrict__ bi3,
               float* __restrict__ out)
{
    __shared__ __align__(16) char smem[32768];       // single buf: A 16K + B 16K
    int t = threadIdx.x;
    int lane = t & 63, wv = t >> 6;
    int wm = wv >> 1, wn = wv & 1;
    int qm = lane & 15, qg = lane >> 4;

    // XCD-aware swizzle: id%8 = XCD (round-robin) -> contiguous 98-block chunk per XCD
    int id = blockIdx.x;
    int wgid = (id & 7)*98 + (id >> 3);
    int byc = wgid & 1;                               // co tile (2) — pair-adjacent
    int bx  = wgid >> 1;                              // pixel tile (392)

    int swz = (((lane & 7) ^ ((lane >> 3) & 7)) << 4);

    uintptr_t gA[4], gB[4];
#pragma unroll
    for (int r = 0; r < 4; ++r) {
        int pixt = r*32 + wv*8 + (lane >> 3);
        int P = bx*128 + pixt;
        int bb = P / HWP, rem = P % HWP;
        int h = rem / WW, w = rem % WW;
        gA[r] = (uintptr_t)xpad + ((size_t)((bb*PH + h + 2)*PW + (w + 2))*DIM)*2 + swz;
        int cog = byc*128 + pixt;
        gB[r] = (uintptr_t)WkT + ((size_t)cog*DIM)*2 + swz;
    }

    f32x4 acc[4][4] = {};

    auto stage = [&](int s) {
        int ch = s / 9, tap = s - ch*9;               // TAP-INNER, CHANNEL-OUTER
        int ky = tap / 3, kx = tap - ky*3;
        int offA = (ky*PW + kx)*(DIM*2) + ch*128;
        int offB = tap*(DIM*DIM*2) + ch*128;
#pragma unroll
        for (int r = 0; r < 4; ++r) {
            __builtin_amdgcn_global_load_lds(
                (const __attribute__((address_space(1))) void*)(gA[r] + offA),
                (__attribute__((address_space(3))) void*)(smem + (r*32 + wv*8)*128),
                16, 0, 0);
            __builtin_amdgcn_global_load_lds(
                (const __attribute__((address_space(1))) void*)(gB[r] + offB),
                (__attribute__((address_space(3))) void*)(smem + 16384 + (r*32 + wv*8)*128),
                16, 0, 0);
        }
    };

    int kxo = (qg << 4) ^ ((lane & 7) << 4);
    auto compute = [&]() {
        const char* pA = smem + (wm*64 + qm)*128;
        const char* pB = smem + 16384 + (wn*64 + qm)*128;
#pragma unroll
        for (int kk = 0; kk < 2; ++kk) {
            int ko = kxo ^ (kk << 6);
            bf16x8 a[4], b[4];
#pragma unroll
            for (int i = 0; i < 4; ++i) {
                a[i] = *(const bf16x8*)(pA + i*2048 + ko);
                b[i] = *(const bf16x8*)(pB + i*2048 + ko);
            }
#pragma unroll
            for (int i = 0; i < 4; ++i)
#pragma unroll
                for (int j = 0; j < 4; ++j)
                    acc[i][j] = __builtin_amdgcn_mfma_f32_16x16x32_bf16(a[i], b[j], acc[i][j], 0, 0, 0);
        }
    };

#define VMW0() asm volatile("s_waitcnt vmcnt(0)" ::: "memory")
#define BARX() { asm volatile("" ::: "memory"); __builtin_amdgcn_s_barrier(); asm volatile("" ::: "memory"); }

#pragma unroll 1
    for (int s = 0; s < 36; ++s) {
        stage(s);                         // issue this step's 8 loads
        VMW0(); BARX();                   // data landed & published (other blocks fill)
        compute();
        BARX();                           // all waves done reading before next overwrite
    }
#undef VMW0
#undef BARX

    // ---- epilogue: per-wave transpose through LDS -> coalesced NCHW stores ----
    float* ep = (float*)smem + wv*1088;               // 64 co x 16 pix, stride 17
#pragma unroll
    for (int mi = 0; mi < 4; ++mi) {
#pragma unroll
        for (int ni = 0; ni < 4; ++ni)
#pragma unroll
            for (int r = 0; r < 4; ++r)
                ep[(ni*16 + qm)*17 + 4*qg + r] = acc[mi][ni][r];
        __syncthreads();
        int P = bx*128 + wm*64 + mi*16 + qm;          // this lane's pixel
        int bb = P / HWP, rem = P % HWP;
        size_t obase = (size_t)bb*DIM*HWP + rem;
#pragma unroll
        for (int j = 0; j < 16; ++j) {
            int col = j*4 + qg;                       // 0..63 within wave's co range
            int cog = byc*128 + wn*64 + col;
            float z = ep[col*17 + qm] + biasm[cog];
            float rep = silu_f(z);
            float y = rep + bf2f(dwo[obase + (size_t)cog*HWP]);
            float yy = y * sc3[cog] + bi3[cog];
            out[obase + (size_t)cog*HWP] = silu_f(yy);
        }
        __syncthreads();
    }
}

// ---------------- launch ----------------
extern "C" void kernel_launch(void* const* d_in, const int* in_sizes, int n_in,
                              void* d_out, int out_size, void* d_ws, size_t ws_size,
                              hipStream_t stream)
{
    (void)in_sizes; (void)n_in; (void)out_size; (void)ws_size;
    const float* x   = (const float*)d_in[0];
    const float* w3  = (const float*)d_in[1];
    const float* g1  = (const float*)d_in[2];
    const float* b1  = (const float*)d_in[3];
    const float* m1  = (const float*)d_in[4];
    const float* v1  = (const float*)d_in[5];
    const float* w1  = (const float*)d_in[6];
    const float* g2  = (const float*)d_in[7];
    const float* b2  = (const float*)d_in[8];
    const float* m2  = (const float*)d_in[9];
    const float* v2  = (const float*)d_in[10];
    const float* dw7 = (const float*)d_in[11];
    const float* dwk = (const float*)d_in[12];
    const float* g3  = (const float*)d_in[13];
    const float* b3  = (const float*)d_in[14];
    const float* m3  = (const float*)d_in[15];
    const float* v3  = (const float*)d_in[16];
    float* out = (float*)d_out;

    char* ws = (char*)d_ws;
    unsigned short* xpad = (unsigned short*)(ws);                 // 16*62*62*256*2 = 31,490,048
    unsigned short* WkT  = (unsigned short*)(ws + 31490048);      // 9*256*256*2    =  1,179,648
    unsigned short* dwo  = (unsigned short*)(ws + 32669696);      // 16*256*3136*2  = 25,690,112
    float* biasm = (float*)(ws + 58359808);
    float* sc3   = (float*)(ws + 58360832);
    float* bi3   = (float*)(ws + 58361856);                       // end ~58.4 MB

    fused_prep<<<dim3(8320), dim3(256), 0, stream>>>(
        x, w3, g1, b1, m1, v1, w1, g2, b2, m2, v2, dw7, dwk, g3, b3, m3, v3,
        xpad, WkT, dwo, biasm, sc3, bi3);
    main_conv<<<dim3(784), dim3(256), 0, stream>>>(xpad, WkT, dwo, biasm, sc3, bi3, out);
}